// Round 3
// baseline (1568.308 us; speedup 1.0000x reference)
//
#include <hip/hip_runtime.h>
#include <hip/hip_bf16.h>
#include <stdint.h>

// Problem dims (fixed instance)
#define N_ROWS 6272      // B*H*W = 8*28*28
#define DIM    1024
#define M_ROWS 16384
#define KNN    9
#define BM     128
#define BN     128
#define BK     64
#define TOPC   6         // candidates kept per (row, 128-col tile, parity)
#define NCAND  (128 * 2 * TOPC)  // 1536 per row
#define TRR    16        // rerank count

typedef __attribute__((ext_vector_type(4))) float f32x4;
typedef __attribute__((ext_vector_type(8))) short short8;

__device__ __forceinline__ unsigned short f2bf(float f) {
  union { float f; unsigned int u; } v; v.f = f;
  unsigned int u = v.u;
  return (unsigned short)((u + 0x7FFFu + ((u >> 16) & 1u)) >> 16); // RNE
}

__device__ __forceinline__ void async16(const void* g, void* l) {
  __builtin_amdgcn_global_load_lds(
      (const __attribute__((address_space(1))) unsigned int*)g,
      (__attribute__((address_space(3))) unsigned int*)l, 16, 0, 0);
}

// order-preserving float->uint (ascending float -> ascending uint)
__device__ __forceinline__ unsigned f2ord(float f) {
  unsigned u = __float_as_uint(f);
  return u ^ (0x80000000u + (u >> 31) * 0x7FFFFFFFu);
}

// ---- x = NCHW -> [N, D] transpose, fp32 + bf16 copies ----
__global__ void k_prep_x(const float* __restrict__ feat,
                         float* __restrict__ xf, unsigned short* __restrict__ xb) {
  const int n = blockIdx.x;
  const int b = n / 784, hw = n % 784;
  const float* src = feat + (size_t)b * (1024 * 784) + hw;  // stride 784 over c
  float* xrow = xf + (size_t)n * DIM;
  unsigned short* brow = xb + (size_t)n * DIM;
  for (int c = threadIdx.x; c < DIM; c += 256) {
    float v = src[(size_t)c * 784];
    xrow[c] = v;
    brow[c] = f2bf(v);
  }
}

// ---- memory bank: bf16 copy + row squared norms ----
__global__ void k_prep_m(const float* __restrict__ mb,
                         unsigned short* __restrict__ mbb, float* __restrict__ mnorm) {
  const int j = blockIdx.x;
  const int t = threadIdx.x;
  const float* src = mb + (size_t)j * DIM;
  unsigned short* dst = mbb + (size_t)j * DIM;
  float s = 0.f;
  for (int c = t; c < DIM; c += 256) {
    float v = src[c];
    dst[c] = f2bf(v);
    s += v * v;
  }
  __shared__ float red[4];
#pragma unroll
  for (int o = 32; o >= 1; o >>= 1) s += __shfl_down(s, o);
  if ((t & 63) == 0) red[t >> 6] = s;
  __syncthreads();
  if (t == 0) mnorm[j] = red[0] + red[1] + red[2] + red[3];
}

// ---- bf16 MFMA distance GEMM, 128x128 tile per block, top-6 epilogue ----
// A/B variants: USE_DMA=true  -> global_load_lds, linear LDS dest, swizzled SOURCE
//               USE_DMA=false -> global->VGPR->ds_write at swizzled dest
// Both: fragment reads at XOR-swizzled addresses (T2; kills the 8e7 bank conflicts).
template <bool USE_DMA>
__launch_bounds__(256, 2)
__global__ void k_score_t(const unsigned short* __restrict__ xb,
                          const unsigned short* __restrict__ mbb,
                          const float* __restrict__ mnorm,
                          unsigned int* __restrict__ cand, int jb0) {
  __shared__ unsigned short Abuf[BM * BK];  // 16 KB
  __shared__ unsigned short Bbuf[BN * BK];  // 16 KB
  __shared__ float mns[BN];
  float* Kbuf = (float*)Abuf;               // aliased after K-loop

  const int bx = blockIdx.x;
  const int orig = (bx & 7) * 392 + (bx >> 3);   // bijective XCD swizzle (3136 = 8*392)
  const int rb = orig >> 6;        // [0,49)
  const int jb = jb0 + (orig & 63);
  const int r0 = rb * BM, j0 = jb * BN;
  const int t  = threadIdx.x;
  const int lane = t & 63, w = t >> 6;
  const int wr = w >> 1, wc = w & 1;
  const int l15 = lane & 15, lg = lane >> 4;

  // staging geometry: 4 chunks of 16B per thread per operand
  int grow[4], colLin[4], colSwz[4], soff[4], swoff[4];
#pragma unroll
  for (int cpy = 0; cpy < 4; ++cpy) {
    const int off = cpy * 2048 + w * 512 + lane * 8;   // shorts, linear LDS order
    const int row = off >> 6;
    grow[cpy]   = row * DIM;
    colLin[cpy] = off & 63;
    colSwz[cpy] = (off & 63) ^ ((row & 7) << 3);
    soff[cpy]   = off;
    swoff[cpy]  = off ^ ((row & 7) << 3);
  }

  f32x4 acc[4][4];
#pragma unroll
  for (int mi = 0; mi < 4; ++mi)
#pragma unroll
    for (int ni = 0; ni < 4; ++ni) acc[mi][ni] = (f32x4){0.f, 0.f, 0.f, 0.f};

#pragma unroll 1
  for (int kk = 0; kk < DIM; kk += BK) {
    const unsigned short* ga = xb  + (size_t)r0 * DIM + kk;
    const unsigned short* gb = mbb + (size_t)j0 * DIM + kk;
    if constexpr (USE_DMA) {
      __syncthreads();
#pragma unroll
      for (int cpy = 0; cpy < 4; ++cpy) {
        async16(ga + grow[cpy] + colSwz[cpy], Abuf + soff[cpy]);
        async16(gb + grow[cpy] + colSwz[cpy], Bbuf + soff[cpy]);
      }
      __syncthreads();
    } else {
      short8 ra[4], rbv[4];
#pragma unroll
      for (int cpy = 0; cpy < 4; ++cpy) {
        ra[cpy]  = *(const short8*)(ga + grow[cpy] + colLin[cpy]);
        rbv[cpy] = *(const short8*)(gb + grow[cpy] + colLin[cpy]);
      }
      __syncthreads();   // previous tile's readers done
#pragma unroll
      for (int cpy = 0; cpy < 4; ++cpy) {
        *(short8*)(Abuf + swoff[cpy]) = ra[cpy];
        *(short8*)(Bbuf + swoff[cpy]) = rbv[cpy];
      }
      __syncthreads();
    }
#pragma unroll
    for (int k2 = 0; k2 < 2; ++k2) {
      const int krun = k2 * 32 + lg * 8;
      short8 af[4], bf[4];
#pragma unroll
      for (int mi = 0; mi < 4; ++mi) {
        const int row = wr * 64 + mi * 16 + l15;
        af[mi] = *(const short8*)(Abuf + ((row * 64 + krun) ^ ((row & 7) << 3)));
      }
#pragma unroll
      for (int ni = 0; ni < 4; ++ni) {
        const int row = wc * 64 + ni * 16 + l15;
        bf[ni] = *(const short8*)(Bbuf + ((row * 64 + krun) ^ ((row & 7) << 3)));
      }
#pragma unroll
      for (int mi = 0; mi < 4; ++mi)
#pragma unroll
        for (int ni = 0; ni < 4; ++ni)
          acc[mi][ni] = __builtin_amdgcn_mfma_f32_16x16x32_bf16(af[mi], bf[ni], acc[mi][ni], 0, 0, 0);
    }
  }

  // ---- epilogue: stage keys 32 cols at a time, per-thread top-6 (packed) ----
  if (t < BN) mns[t] = mnorm[j0 + t];
  const int srow = t >> 1;         // scan row [0,128)
  const int cp   = t & 1;          // column parity
  unsigned tk[TOPC];
#pragma unroll
  for (int s = 0; s < TOPC; ++s) tk[s] = 0xFFFFFFFFu;
  unsigned tmax = 0xFFFFFFFFu;

#pragma unroll 1
  for (int st = 0; st < 4; ++st) {
    __syncthreads();   // covers mns visibility + Abuf->Kbuf alias safety
    if (wc == (st >> 1)) {
      const int nip = (st & 1) * 2;
#pragma unroll
      for (int mi = 0; mi < 4; ++mi) {
        const int rbase = wr * 64 + mi * 16 + lg * 4;
#pragma unroll
        for (int nq = 0; nq < 2; ++nq) {
          const int ni = nip + nq;
          const int colL = nq * 16 + l15;
          const float mn = mns[(st >> 1) * 64 + ni * 16 + l15];
#pragma unroll
          for (int e = 0; e < 4; ++e)
            Kbuf[(rbase + e) * 32 + colL] = mn - 2.0f * acc[mi][ni][e];
        }
      }
    }
    __syncthreads();
#pragma unroll 1
    for (int cc = 0; cc < 16; ++cc) {
      const int c = 2 * ((cc + srow) & 15) + cp;   // bank-staggered, parity-split
      const float key = Kbuf[srow * 32 + c];
      const unsigned p = (f2ord(key) & 0xFFFFC000u) | (unsigned)(j0 + st * 32 + c);
      if (p < tmax) {
        int ms = 0; unsigned mv = tk[0];
#pragma unroll
        for (int s = 1; s < TOPC; ++s) if (tk[s] > mv) { mv = tk[s]; ms = s; }
#pragma unroll
        for (int s = 0; s < TOPC; ++s) if (s == ms) tk[s] = p;
        mv = tk[0];
#pragma unroll
        for (int s = 1; s < TOPC; ++s) mv = mv > tk[s] ? mv : tk[s];
        tmax = mv;
      }
    }
  }
  {
    const size_t base = ((size_t)(r0 + srow) * 256 + (size_t)jb * 2 + cp) * TOPC;
#pragma unroll
    for (int s = 0; s < TOPC; ++s) cand[base + s] = tk[s];
  }
}

// ---- merge 1536 packed candidates -> exact-by-key top-16 -> fp64 rerank -> top-9 ----
__global__ void k_rerank(const float* __restrict__ xf, const float* __restrict__ mb,
                         const unsigned int* __restrict__ cand,
                         int* __restrict__ idx9, double* __restrict__ dsv) {
  const int n = blockIdx.x, t = threadIdx.x;
  __shared__ float    xs[DIM];
  __shared__ unsigned cs[NCAND];
  __shared__ unsigned sel[TRR];
  __shared__ double dpart[256];
  __shared__ double d2s[TRR];
  __shared__ double dist_s[TRR];
  __shared__ int    rank_s[TRR];

  const float* xrow = xf + (size_t)n * DIM;
  for (int c = t; c < DIM; c += 256) xs[c] = xrow[c];
  const size_t cb = (size_t)n * NCAND;
  for (int s = t; s < NCAND; s += 256) cs[s] = cand[cb + s];
  __syncthreads();

  if (t < 64) {  // wave 0: 64 lanes x 24 items, 16 extract-min rounds
    unsigned ck[24];
#pragma unroll
    for (int s = 0; s < 24; ++s) ck[s] = cs[t + 64 * s];
    for (int it = 0; it < TRR; ++it) {
      unsigned best = ck[0];
#pragma unroll
      for (int s = 1; s < 24; ++s) best = best < ck[s] ? best : ck[s];
#pragma unroll
      for (int off = 32; off >= 1; off >>= 1) {
        const unsigned o = (unsigned)__shfl_xor((int)best, off);
        best = best < o ? best : o;
      }
      if (t == 0) sel[it] = best;
#pragma unroll
      for (int s = 0; s < 24; ++s) if (ck[s] == best) ck[s] = 0xFFFFFFFFu;
    }
  }
  __syncthreads();
  {
    const int s = t >> 4, l16 = t & 15;
    const int j = (int)(sel[s] & 16383u);
    const float* mrow = mb + (size_t)j * DIM;
    double a = 0.0;
    for (int i = 0; i < 64; ++i) {
      const int c = l16 + (i << 4);
      const double d = (double)xs[c] - (double)mrow[c];
      a += d * d;
    }
    dpart[t] = a;
  }
  __syncthreads();
  if (t < TRR) {
    double v = 0.0;
    for (int i = 0; i < 16; ++i) v += dpart[t * 16 + i];
    d2s[t] = v;
    dist_s[t] = sqrt(v < 1e-12 ? 1e-12 : v);
  }
  __syncthreads();
  if (t < TRR) {
    const double v = d2s[t]; const int id = (int)(sel[t] & 16383u);
    int r = 0;
    for (int u = 0; u < TRR; ++u) {
      const double vu = d2s[u];
      const int idu = (int)(sel[u] & 16383u);
      if (vu < v || (vu == v && idu < id)) ++r;
    }
    rank_s[t] = r;
    if (r < KNN) idx9[n * KNN + r] = id;
  }
  __syncthreads();
  if (t == 0) {
    double sum = 0.0;
    for (int u = 0; u < TRR; ++u) if (rank_s[u] < KNN) sum += dist_s[u];
    dsv[n] = sum * (1.0 / KNN);
  }
}

// ---- global mean/std of per-row mean distance ----
__global__ void k_dsstats(const double* __restrict__ dsv, double* __restrict__ stats) {
  __shared__ double red[256];
  const int t = threadIdx.x;
  double s = 0.0;
  for (int i = t; i < N_ROWS; i += 256) s += dsv[i];
  red[t] = s; __syncthreads();
  for (int o = 128; o >= 1; o >>= 1) { if (t < o) red[t] += red[t + o]; __syncthreads(); }
  const double mean = red[0] / (double)N_ROWS;
  __syncthreads();
  double v = 0.0;
  for (int i = t; i < N_ROWS; i += 256) { const double d = dsv[i] - mean; v += d * d; }
  red[t] = v; __syncthreads();
  for (int o = 128; o >= 1; o >>= 1) { if (t < o) red[t] += red[t + o]; __syncthreads(); }
  if (t == 0) {
    const double fullstd = sqrt(red[0] * (double)DIM / ((double)N_ROWS * DIM - 1.0));
    stats[0] = mean;
    stats[1] = fullstd + 1e-8;
  }
}

// ---- influence, row-norm, sigmoid noise, noised output + maps ----
__global__ void k_final(const float* __restrict__ xf, const float* __restrict__ mb,
                        const float* __restrict__ iw, const float* __restrict__ dwp,
                        const float* __restrict__ eps, const int* __restrict__ idx9,
                        const double* __restrict__ dsv, const double* __restrict__ stats,
                        float* __restrict__ out) {
  const int n = blockIdx.x, t = threadIdx.x;
  __shared__ float xs[DIM];
  __shared__ int js[KNN];
  __shared__ float rs1[4], rs2[4];
  const float* xrow = xf + (size_t)n * DIM;
  for (int c = t; c < DIM; c += 256) xs[c] = xrow[c];
  if (t < KNN) js[t] = idx9[n * KNN + t];
  __syncthreads();

  float infl[4];
  float s1 = 0.f, s2 = 0.f;
#pragma unroll
  for (int q = 0; q < 4; ++q) {
    const int c = t + q * 256;
    const float x = xs[c];
    float a = 0.f;
#pragma unroll
    for (int k = 0; k < KNN; ++k) a += fabsf(x - mb[(size_t)js[k] * DIM + c]);
    const float v = a * (1.0f / KNN) * iw[c];
    infl[q] = v; s1 += v; s2 += v * v;
  }
#pragma unroll
  for (int o = 32; o >= 1; o >>= 1) { s1 += __shfl_down(s1, o); s2 += __shfl_down(s2, o); }
  if ((t & 63) == 0) { rs1[t >> 6] = s1; rs2[t >> 6] = s2; }
  __syncthreads();
  const float sum = rs1[0] + rs1[1] + rs1[2] + rs1[3];
  const float sq  = rs2[0] + rs2[1] + rs2[2] + rs2[3];
  const float mean = sum * (1.0f / DIM);
  float var = (sq - (float)DIM * mean * mean) * (1.0f / (DIM - 1));
  var = fmaxf(var, 0.f);
  const float inv = 1.0f / (sqrtf(var) + 1e-8f);
  const float dn = (float)(((double)dsv[n] - stats[0]) / stats[1]);
  const float zb = dwp[0] * dn;

  const int b = n / 784, hw = n % 784;
  float* op = out + (size_t)b * (1024 * 784) + hw;
  const float* ep = eps + (size_t)n * DIM;
  float si = 0.f, sn = 0.f;
#pragma unroll
  for (int q = 0; q < 4; ++q) {
    const int c = t + q * 256;
    const float v = infl[q];
    const float z = (v - mean) * inv + zb;
    const float ns = 0.01f + 0.49f / (1.0f + expf(-z));
    op[(size_t)c * 784] = xs[c] + ep[c] * ns;
    si += v; sn += ns;
  }
  __syncthreads();  // rs1/rs2 reads above complete before reuse
#pragma unroll
  for (int o = 32; o >= 1; o >>= 1) { si += __shfl_down(si, o); sn += __shfl_down(sn, o); }
  if ((t & 63) == 0) { rs1[t >> 6] = si; rs2[t >> 6] = sn; }
  __syncthreads();
  if (t == 0) {
    out[6422528 + n]        = (rs1[0] + rs1[1] + rs1[2] + rs1[3]) * (1.0f / DIM);
    out[6422528 + 6272 + n] = (rs2[0] + rs2[1] + rs2[2] + rs2[3]) * (1.0f / DIM);
  }
}

extern "C" void kernel_launch(void* const* d_in, const int* in_sizes, int n_in,
                              void* d_out, int out_size, void* d_ws, size_t ws_size,
                              hipStream_t stream) {
  (void)in_sizes; (void)n_in; (void)out_size; (void)ws_size;
  const float* feat = (const float*)d_in[0];
  const float* mb   = (const float*)d_in[1];
  const float* iw   = (const float*)d_in[2];
  const float* dw   = (const float*)d_in[3];
  const float* eps  = (const float*)d_in[4];
  float* out = (float*)d_out;

  char* p = (char*)d_ws;
  float* xf = (float*)p;                     p += (size_t)N_ROWS * DIM * 4;
  unsigned short* xbf = (unsigned short*)p;  p += (size_t)N_ROWS * DIM * 2;
  unsigned short* mbb = (unsigned short*)p;  p += (size_t)M_ROWS * DIM * 2;
  float* mnorm = (float*)p;                  p += (size_t)M_ROWS * 4;
  unsigned int* cand = (unsigned int*)p;     p += (size_t)N_ROWS * NCAND * 4;
  int* idx9 = (int*)p;                       p += (size_t)N_ROWS * KNN * 4;
  p = (char*)(((uintptr_t)p + 255) & ~(uintptr_t)255);
  double* dsv = (double*)p;                  p += (size_t)N_ROWS * 8;
  double* stats = (double*)p;                p += 64;
  // total ~111 MB of d_ws

  k_prep_x<<<N_ROWS, 256, 0, stream>>>(feat, xf, xbf);
  k_prep_m<<<M_ROWS, 256, 0, stream>>>(mb, mbb, mnorm);
  // A/B: j-halves, identical math, staging mechanism differs
  k_score_t<true ><<<49 * 64, 256, 0, stream>>>(xbf, mbb, mnorm, cand, 0);   // LDS-DMA
  k_score_t<false><<<49 * 64, 256, 0, stream>>>(xbf, mbb, mnorm, cand, 64);  // reg-staged
  k_rerank<<<N_ROWS, 256, 0, stream>>>(xf, mb, cand, idx9, dsv);
  k_dsstats<<<1, 256, 0, stream>>>(dsv, stats);
  k_final<<<N_ROWS, 256, 0, stream>>>(xf, mb, iw, dw, eps, idx9, dsv, stats, out);
}

// Round 4
// 611.286 us; speedup vs baseline: 2.5656x; 2.5656x over previous
//
#include <hip/hip_runtime.h>
#include <hip/hip_bf16.h>
#include <stdint.h>

// Problem dims (fixed instance)
#define N_ROWS 6272      // B*H*W = 8*28*28
#define DIM    1024
#define M_ROWS 16384
#define KNN    9
#define BMS    256       // score tile M
#define BNS    256       // score tile N
#define BKS    64
#define NJB    64        // M_ROWS / BNS
#define TOPC   6         // candidates kept per (row, j-block, parity)
#define NCAND  (NJB * 2 * TOPC)   // 768 per row
#define TRR    16        // rerank count

typedef __attribute__((ext_vector_type(4))) float f32x4;
typedef __attribute__((ext_vector_type(8))) short short8;

__device__ __forceinline__ unsigned short f2bf(float f) {
  union { float f; unsigned int u; } v; v.f = f;
  unsigned int u = v.u;
  return (unsigned short)((u + 0x7FFFu + ((u >> 16) & 1u)) >> 16); // RNE
}

__device__ __forceinline__ void async16(const void* g, void* l) {
  __builtin_amdgcn_global_load_lds(
      (const __attribute__((address_space(1))) unsigned int*)g,
      (__attribute__((address_space(3))) unsigned int*)l, 16, 0, 0);
}

// order-preserving float->uint (ascending float -> ascending uint)
__device__ __forceinline__ unsigned f2ord(float f) {
  unsigned u = __float_as_uint(f);
  return u ^ (0x80000000u + (u >> 31) * 0x7FFFFFFFu);
}

// ---- x = NCHW -> [N, D] transpose, fp32 + bf16 copies ----
__global__ void k_prep_x(const float* __restrict__ feat,
                         float* __restrict__ xf, unsigned short* __restrict__ xb) {
  const int n = blockIdx.x;
  const int b = n / 784, hw = n % 784;
  const float* src = feat + (size_t)b * (1024 * 784) + hw;  // stride 784 over c
  float* xrow = xf + (size_t)n * DIM;
  unsigned short* brow = xb + (size_t)n * DIM;
  for (int c = threadIdx.x; c < DIM; c += 256) {
    float v = src[(size_t)c * 784];
    xrow[c] = v;
    brow[c] = f2bf(v);
  }
}

// ---- memory bank: bf16 copy + row squared norms ----
__global__ void k_prep_m(const float* __restrict__ mb,
                         unsigned short* __restrict__ mbb, float* __restrict__ mnorm) {
  const int j = blockIdx.x;
  const int t = threadIdx.x;
  const float* src = mb + (size_t)j * DIM;
  unsigned short* dst = mbb + (size_t)j * DIM;
  float s = 0.f;
  for (int c = t; c < DIM; c += 256) {
    float v = src[c];
    dst[c] = f2bf(v);
    s += v * v;
  }
  __shared__ float red[4];
#pragma unroll
  for (int o = 32; o >= 1; o >>= 1) s += __shfl_down(s, o);
  if ((t & 63) == 0) red[t >> 6] = s;
  __syncthreads();
  if (t == 0) mnorm[j] = red[0] + red[1] + red[2] + red[3];
}

// ---- bf16 MFMA distance GEMM, 256x256 tile, XCD-panel-persistent blocks ----
// 256 blocks (1/CU). Block owns j-panel jb (=xcd*8+jbl) and a row-quarter;
// per XCD the 8 jb-panels (4 MB of B) stay L2-resident across the row sweep.
// Double-buffered K-loop (stage next || compute current). Epilogue-only top-6.
__launch_bounds__(512, 2)
__global__ void k_score(const unsigned short* __restrict__ xb,
                        const unsigned short* __restrict__ mbb,
                        const float* __restrict__ mnorm,
                        unsigned int* __restrict__ cand) {
  __shared__ unsigned short S[4 * 16384];   // A0,A1,B0,B1 : 32 KB each = 128 KB
  __shared__ float mns[BNS];
  float* Kbuf = (float*)S;                  // 64 KB epilogue key staging (aliases A0/A1)

  const int bx = blockIdx.x;
  const int xcd = bx & 7, u = bx >> 3;      // dispatch round-robins XCDs
  const int jbl = u & 7, rq = u >> 3;       // jbl in [0,8), rq in [0,4)
  const int jb = xcd * 8 + jbl;             // [0,64)
  const int j0 = jb * BNS;
  const int rstart4[4] = {0, 7, 13, 19};
  const int rcount4[4] = {7, 6, 6, 6};
  const int rstart = rstart4[rq], rcount = rcount4[rq];

  const int t = threadIdx.x;
  const int lane = t & 63, w = t >> 6;
  const int wr = w >> 2, wc2 = w & 3;       // wave grid 2 x 4
  const int l15 = lane & 15, lg = lane >> 4;
  const int srow = t >> 1, cp = t & 1;      // epilogue scan row/parity

  // staging geometry: 4 x 16B chunks per thread per operand, linear LDS,
  // XOR-swizzled SOURCE column (matched by swizzled fragment reads)
  int rowL[4], ldsOff[4], colSwz[4];
  const unsigned short* bSrc[4];
#pragma unroll
  for (int cpy = 0; cpy < 4; ++cpy) {
    const int off = cpy * 4096 + t * 8;     // shorts
    const int row = off >> 6;
    rowL[cpy] = row;
    ldsOff[cpy] = off;
    colSwz[cpy] = (off & 63) ^ ((row & 7) << 3);
    bSrc[cpy] = mbb + (size_t)(j0 + row) * DIM + colSwz[cpy];
  }
  if (t < BNS) mns[t] = mnorm[j0 + t];

#pragma unroll 1
  for (int ri = 0; ri < rcount; ++ri) {
    const int r0 = (rstart + ri) * BMS;
    const unsigned short* aSrc[4];
#pragma unroll
    for (int cpy = 0; cpy < 4; ++cpy) {
      int rg = r0 + rowL[cpy];
      rg = rg < N_ROWS ? rg : (N_ROWS - 1);   // clamp tail rows (stores guarded)
      aSrc[cpy] = xb + (size_t)rg * DIM + colSwz[cpy];
    }

    f32x4 acc[8][4];
#pragma unroll
    for (int mi = 0; mi < 8; ++mi)
#pragma unroll
      for (int ni = 0; ni < 4; ++ni) acc[mi][ni] = (f32x4){0.f, 0.f, 0.f, 0.f};

    // prologue: stage K-step 0 into buf0
#pragma unroll
    for (int cpy = 0; cpy < 4; ++cpy) {
      async16(aSrc[cpy], S + ldsOff[cpy]);
      async16(bSrc[cpy], S + 32768 + ldsOff[cpy]);
    }
    __syncthreads();
    int cur = 0;
#pragma unroll 1
    for (int ks = 0; ks < 16; ++ks) {
      if (ks < 15) {                           // stage next K-step into other buf
        const int kk = (ks + 1) * BKS;
        const int nb = (cur ^ 1) * 16384;
#pragma unroll
        for (int cpy = 0; cpy < 4; ++cpy) {
          async16(aSrc[cpy] + kk, S + nb + ldsOff[cpy]);
          async16(bSrc[cpy] + kk, S + 32768 + nb + ldsOff[cpy]);
        }
      }
      const unsigned short* Ab = S + cur * 16384;
      const unsigned short* Bb = S + 32768 + cur * 16384;
#pragma unroll
      for (int k2 = 0; k2 < 2; ++k2) {
        const int slot = (k2 * 32 + lg * 8) ^ ((l15 & 7) << 3);
        short8 af[8], bf[4];
#pragma unroll
        for (int mi = 0; mi < 8; ++mi)
          af[mi] = *(const short8*)(Ab + (wr * 128 + mi * 16 + l15) * 64 + slot);
#pragma unroll
        for (int ni = 0; ni < 4; ++ni)
          bf[ni] = *(const short8*)(Bb + (wc2 * 64 + ni * 16 + l15) * 64 + slot);
#pragma unroll
        for (int mi = 0; mi < 8; ++mi)
#pragma unroll
          for (int ni = 0; ni < 4; ++ni)
            acc[mi][ni] = __builtin_amdgcn_mfma_f32_16x16x32_bf16(af[mi], bf[ni], acc[mi][ni], 0, 0, 0);
      }
      __syncthreads();   // drains next-buf DMAs; all waves done reading cur
      cur ^= 1;
    }

    // ---- epilogue: 4 stages of 64 cols; per-thread top-6 packed ----
    unsigned tk[TOPC];
#pragma unroll
    for (int s = 0; s < TOPC; ++s) tk[s] = 0xFFFFFFFFu;
    unsigned tmax = 0xFFFFFFFFu;

#pragma unroll 1
    for (int st = 0; st < 4; ++st) {
      if (wc2 == st) {       // 2 waves write all 256 rows x 64 cols of keys
#pragma unroll
        for (int mi = 0; mi < 8; ++mi) {
#pragma unroll
          for (int ni = 0; ni < 4; ++ni) {
            const float mn = mns[st * 64 + ni * 16 + l15];
#pragma unroll
            for (int e = 0; e < 4; ++e) {
              const int row = wr * 128 + mi * 16 + lg * 4 + e;
              Kbuf[row * 64 + ni * 16 + l15] = mn - 2.0f * acc[mi][ni][e];
            }
          }
        }
      }
      __syncthreads();
      const int jbase = j0 + st * 64;
#pragma unroll 1
      for (int cc = 0; cc < 32; ++cc) {
        const int c = 2 * ((cc + srow) & 31) + cp;   // bank-staggered, parity-split
        const float key = Kbuf[srow * 64 + c];
        const unsigned p = (f2ord(key) & 0xFFFFC000u) | (unsigned)(jbase + c);
        if (p < tmax) {
          int ms = 0; unsigned mv = tk[0];
#pragma unroll
          for (int s = 1; s < TOPC; ++s) if (tk[s] > mv) { mv = tk[s]; ms = s; }
#pragma unroll
          for (int s = 0; s < TOPC; ++s) if (s == ms) tk[s] = p;
          mv = tk[0];
#pragma unroll
          for (int s = 1; s < TOPC; ++s) mv = mv > tk[s] ? mv : tk[s];
          tmax = mv;
        }
      }
      __syncthreads();   // scan done before Kbuf overwrite / next staging
    }
    if (r0 + srow < N_ROWS) {
      const size_t base = (size_t)(r0 + srow) * NCAND + (size_t)(jb * 2 + cp) * TOPC;
#pragma unroll
      for (int s = 0; s < TOPC; ++s) cand[base + s] = tk[s];
    }
  }
}

// ---- merge 768 packed candidates -> exact-by-key top-16 -> fp64 rerank -> top-9 ----
__global__ void k_rerank(const float* __restrict__ xf, const float* __restrict__ mb,
                         const unsigned int* __restrict__ cand,
                         int* __restrict__ idx9, double* __restrict__ dsv) {
  const int n = blockIdx.x, t = threadIdx.x;
  __shared__ float    xs[DIM];
  __shared__ unsigned cs[NCAND];
  __shared__ unsigned sel[TRR];
  __shared__ double dpart[256];
  __shared__ double d2s[TRR];
  __shared__ double dist_s[TRR];
  __shared__ int    rank_s[TRR];

  const float* xrow = xf + (size_t)n * DIM;
  for (int c = t; c < DIM; c += 256) xs[c] = xrow[c];
  const size_t cb = (size_t)n * NCAND;
  for (int s = t; s < NCAND; s += 256) cs[s] = cand[cb + s];
  __syncthreads();

  if (t < 64) {  // wave 0: 64 lanes x 12 items, 16 extract-min rounds
    unsigned ck[12];
#pragma unroll
    for (int s = 0; s < 12; ++s) ck[s] = cs[t + 64 * s];
    for (int it = 0; it < TRR; ++it) {
      unsigned best = ck[0];
#pragma unroll
      for (int s = 1; s < 12; ++s) best = best < ck[s] ? best : ck[s];
#pragma unroll
      for (int off = 32; off >= 1; off >>= 1) {
        const unsigned o = (unsigned)__shfl_xor((int)best, off);
        best = best < o ? best : o;
      }
      if (t == 0) sel[it] = best;
#pragma unroll
      for (int s = 0; s < 12; ++s) if (ck[s] == best) ck[s] = 0xFFFFFFFFu;
    }
  }
  __syncthreads();
  {
    const int s = t >> 4, l16 = t & 15;
    const int j = (int)(sel[s] & 16383u);
    const float* mrow = mb + (size_t)j * DIM;
    double a = 0.0;
    for (int i = 0; i < 64; ++i) {
      const int c = l16 + (i << 4);
      const double d = (double)xs[c] - (double)mrow[c];
      a += d * d;
    }
    dpart[t] = a;
  }
  __syncthreads();
  if (t < TRR) {
    double v = 0.0;
    for (int i = 0; i < 16; ++i) v += dpart[t * 16 + i];
    d2s[t] = v;
    dist_s[t] = sqrt(v < 1e-12 ? 1e-12 : v);
  }
  __syncthreads();
  if (t < TRR) {
    const double v = d2s[t]; const int id = (int)(sel[t] & 16383u);
    int r = 0;
    for (int u = 0; u < TRR; ++u) {
      const double vu = d2s[u];
      const int idu = (int)(sel[u] & 16383u);
      if (vu < v || (vu == v && idu < id)) ++r;
    }
    rank_s[t] = r;
    if (r < KNN) idx9[n * KNN + r] = id;
  }
  __syncthreads();
  if (t == 0) {
    double sum = 0.0;
    for (int u = 0; u < TRR; ++u) if (rank_s[u] < KNN) sum += dist_s[u];
    dsv[n] = sum * (1.0 / KNN);
  }
}

// ---- global mean/std of per-row mean distance ----
__global__ void k_dsstats(const double* __restrict__ dsv, double* __restrict__ stats) {
  __shared__ double red[256];
  const int t = threadIdx.x;
  double s = 0.0;
  for (int i = t; i < N_ROWS; i += 256) s += dsv[i];
  red[t] = s; __syncthreads();
  for (int o = 128; o >= 1; o >>= 1) { if (t < o) red[t] += red[t + o]; __syncthreads(); }
  const double mean = red[0] / (double)N_ROWS;
  __syncthreads();
  double v = 0.0;
  for (int i = t; i < N_ROWS; i += 256) { const double d = dsv[i] - mean; v += d * d; }
  red[t] = v; __syncthreads();
  for (int o = 128; o >= 1; o >>= 1) { if (t < o) red[t] += red[t + o]; __syncthreads(); }
  if (t == 0) {
    const double fullstd = sqrt(red[0] * (double)DIM / ((double)N_ROWS * DIM - 1.0));
    stats[0] = mean;
    stats[1] = fullstd + 1e-8;
  }
}

// ---- influence, row-norm, sigmoid noise, noised output + maps ----
__global__ void k_final(const float* __restrict__ xf, const float* __restrict__ mb,
                        const float* __restrict__ iw, const float* __restrict__ dwp,
                        const float* __restrict__ eps, const int* __restrict__ idx9,
                        const double* __restrict__ dsv, const double* __restrict__ stats,
                        float* __restrict__ out) {
  const int n = blockIdx.x, t = threadIdx.x;
  __shared__ float xs[DIM];
  __shared__ int js[KNN];
  __shared__ float rs1[4], rs2[4];
  const float* xrow = xf + (size_t)n * DIM;
  for (int c = t; c < DIM; c += 256) xs[c] = xrow[c];
  if (t < KNN) js[t] = idx9[n * KNN + t];
  __syncthreads();

  float infl[4];
  float s1 = 0.f, s2 = 0.f;
#pragma unroll
  for (int q = 0; q < 4; ++q) {
    const int c = t + q * 256;
    const float x = xs[c];
    float a = 0.f;
#pragma unroll
    for (int k = 0; k < KNN; ++k) a += fabsf(x - mb[(size_t)js[k] * DIM + c]);
    const float v = a * (1.0f / KNN) * iw[c];
    infl[q] = v; s1 += v; s2 += v * v;
  }
#pragma unroll
  for (int o = 32; o >= 1; o >>= 1) { s1 += __shfl_down(s1, o); s2 += __shfl_down(s2, o); }
  if ((t & 63) == 0) { rs1[t >> 6] = s1; rs2[t >> 6] = s2; }
  __syncthreads();
  const float sum = rs1[0] + rs1[1] + rs1[2] + rs1[3];
  const float sq  = rs2[0] + rs2[1] + rs2[2] + rs2[3];
  const float mean = sum * (1.0f / DIM);
  float var = (sq - (float)DIM * mean * mean) * (1.0f / (DIM - 1));
  var = fmaxf(var, 0.f);
  const float inv = 1.0f / (sqrtf(var) + 1e-8f);
  const float dn = (float)(((double)dsv[n] - stats[0]) / stats[1]);
  const float zb = dwp[0] * dn;

  const int b = n / 784, hw = n % 784;
  float* op = out + (size_t)b * (1024 * 784) + hw;
  const float* ep = eps + (size_t)n * DIM;
  float si = 0.f, sn = 0.f;
#pragma unroll
  for (int q = 0; q < 4; ++q) {
    const int c = t + q * 256;
    const float v = infl[q];
    const float z = (v - mean) * inv + zb;
    const float ns = 0.01f + 0.49f / (1.0f + expf(-z));
    op[(size_t)c * 784] = xs[c] + ep[c] * ns;
    si += v; sn += ns;
  }
  __syncthreads();  // rs1/rs2 reads above complete before reuse
#pragma unroll
  for (int o = 32; o >= 1; o >>= 1) { si += __shfl_down(si, o); sn += __shfl_down(sn, o); }
  if ((t & 63) == 0) { rs1[t >> 6] = si; rs2[t >> 6] = sn; }
  __syncthreads();
  if (t == 0) {
    out[6422528 + n]        = (rs1[0] + rs1[1] + rs1[2] + rs1[3]) * (1.0f / DIM);
    out[6422528 + 6272 + n] = (rs2[0] + rs2[1] + rs2[2] + rs2[3]) * (1.0f / DIM);
  }
}

extern "C" void kernel_launch(void* const* d_in, const int* in_sizes, int n_in,
                              void* d_out, int out_size, void* d_ws, size_t ws_size,
                              hipStream_t stream) {
  (void)in_sizes; (void)n_in; (void)out_size; (void)ws_size;
  const float* feat = (const float*)d_in[0];
  const float* mb   = (const float*)d_in[1];
  const float* iw   = (const float*)d_in[2];
  const float* dw   = (const float*)d_in[3];
  const float* eps  = (const float*)d_in[4];
  float* out = (float*)d_out;

  char* p = (char*)d_ws;
  float* xf = (float*)p;                     p += (size_t)N_ROWS * DIM * 4;
  unsigned short* xbf = (unsigned short*)p;  p += (size_t)N_ROWS * DIM * 2;
  unsigned short* mbb = (unsigned short*)p;  p += (size_t)M_ROWS * DIM * 2;
  float* mnorm = (float*)p;                  p += (size_t)M_ROWS * 4;
  unsigned int* cand = (unsigned int*)p;     p += (size_t)N_ROWS * NCAND * 4;
  int* idx9 = (int*)p;                       p += (size_t)N_ROWS * KNN * 4;
  p = (char*)(((uintptr_t)p + 255) & ~(uintptr_t)255);
  double* dsv = (double*)p;                  p += (size_t)N_ROWS * 8;
  double* stats = (double*)p;                p += 64;
  // total ~90 MB of d_ws

  k_prep_x<<<N_ROWS, 256, 0, stream>>>(feat, xf, xbf);
  k_prep_m<<<M_ROWS, 256, 0, stream>>>(mb, mbb, mnorm);
  k_score<<<256, 512, 0, stream>>>(xbf, mbb, mnorm, cand);
  k_rerank<<<N_ROWS, 256, 0, stream>>>(xf, mb, cand, idx9, dsv);
  k_dsstats<<<1, 256, 0, stream>>>(dsv, stats);
  k_final<<<N_ROWS, 256, 0, stream>>>(xf, mb, iw, dw, eps, idx9, dsv, stats, out);
}